// Round 7
// baseline (55.309 us; speedup 1.0000x reference)
//
#include <hip/hip_runtime.h>

#define B_    2
#define NWQ   75
#define PQ    196
#define D_    64
#define WAY   5
#define SHOT  5
#define SSUP  980                  // support patches per (b, way)
#define SPAD  1024                 // padded to 64*16 (4 quarters of 256)
#define QROWS_Q 256                // support rows per quarter-block
#define QT_PER  16                 // 16-row tiles per quarter
#define QI_PER_BLK 3
#define QCHUNKS 25                 // 75/3
#define QROWS 588                  // 3*196 query rows per chunk
#define QTILES_BLK 37              // ceil(588/16)
#define NPC  (B_ * WAY * QCHUNKS)  // 250 (pair, chunk) combos
#define NWAVES 16                  // waves per block (1024 threads)

typedef __attribute__((ext_vector_type(8))) short short8;   // 8 bf16 = 4 VGPR
typedef __attribute__((ext_vector_type(4))) float f32x4;

__device__ __forceinline__ ushort f2bf(float f) {
    uint u = __builtin_bit_cast(uint, f);
    u = (u + 0x7FFFu + ((u >> 16) & 1u)) >> 16;
    return (ushort)u;
}
__device__ __forceinline__ float bf2f(ushort u) {
    return __builtin_bit_cast(float, (uint)u << 16);
}

__device__ __forceinline__ short8 pack8(float4 a, float4 b) {
    short8 o;
    o[0] = (short)f2bf(a.x); o[1] = (short)f2bf(a.y);
    o[2] = (short)f2bf(a.z); o[3] = (short)f2bf(a.w);
    o[4] = (short)f2bf(b.x); o[5] = (short)f2bf(b.y);
    o[6] = (short)f2bf(b.z); o[7] = (short)f2bf(b.w);
    return o;
}

// fp32 -> bf16 support panel, padded to [2*5][1024][64], PRE-SWIZZLED on 16B
// units (unit' = u ^ (row&7)) so the main kernel can DMA it linearly into LDS.
__global__ __launch_bounds__(256)
void cvt_s_kernel(const float* __restrict__ in, ushort* __restrict__ out) {
    int i = blockIdx.x * blockDim.x + threadIdx.x;   // one 16B unit (8 bf16)
    const int NU = B_ * WAY * SPAD * 8;              // 81920
    if (i >= NU) return;
    int u  = i & 7;
    int r  = (i >> 3) % SPAD;
    int pr = i / (8 * SPAD);                         // b*WAY + w
    short8 o = {0,0,0,0,0,0,0,0};
    if (r < SSUP) {
        const float* src = in + ((size_t)(pr * SSUP + r) * D_ + u * 8);
        float4 f0 = *(const float4*)src;
        float4 f1 = *(const float4*)(src + 4);
        o = pack8(f0, f1);
    }
    int du = u ^ (r & 7);
    *(short8*)(out + ((size_t)(pr * SPAD + r) * 8 + du) * 8) = o;
}

// Fused per-stream MFMA -> top-3 insert loop over this quarter's tiles.
// NT independent q-tile streams (tile = wid + 16*i). Register cap 64 (incl
// AGPR, unified file) so 2 blocks/CU x 16 waves = 8 waves/SIMD co-resident.
template<int NT>
__device__ __forceinline__ void wave_path(
    const short8* __restrict__ lrow, int u0, int u1, int lg, int lr, int wid,
    int h, const float* __restrict__ Qc, ushort* __restrict__ partBase) {

    short8 bq[NT][2];
    int rows[NT];
    #pragma unroll
    for (int i = 0; i < NT; ++i) {
        int row = (wid + NWAVES * i) * 16 + lr;
        rows[i] = row;
        int rc = (row < QROWS) ? row : 0;
        const float* qrow = Qc + (size_t)rc * D_;
        float4 fa = *(const float4*)(qrow + lg * 8);
        float4 fb = *(const float4*)(qrow + lg * 8 + 4);
        float4 fc = *(const float4*)(qrow + 32 + lg * 8);
        float4 fd = *(const float4*)(qrow + 32 + lg * 8 + 4);
        bq[i][0] = pack8(fa, fb);
        bq[i][1] = pack8(fc, fd);
    }

    float t3[NT][3];
    #pragma unroll
    for (int i = 0; i < NT; ++i) {
        t3[i][0] = -__builtin_inff(); t3[i][1] = -__builtin_inff(); t3[i][2] = -__builtin_inff();
    }

    // drain staging DMA + q loads, then block-wide barrier
    asm volatile("s_waitcnt vmcnt(0)" ::: "memory");
    __syncthreads();

    // ---- clean tiles (no support-row masking): 16 for h<3, 13 for h==3 ----
    const int ntClean = (h == 3) ? (QT_PER - 3) : QT_PER;
    for (int st = 0; st < ntClean; ++st) {
        const short8* p = lrow + st * 128;   // 16 rows x 8 units per tile
        short8 A0 = p[u0];
        short8 A1 = p[u1];
        #pragma unroll
        for (int i = 0; i < NT; ++i) {
            f32x4 cc = {0.f, 0.f, 0.f, 0.f};
            cc = __builtin_amdgcn_mfma_f32_16x16x32_bf16(A0, bq[i][0], cc, 0, 0, 0);
            cc = __builtin_amdgcn_mfma_f32_16x16x32_bf16(A1, bq[i][1], cc, 0, 0, 0);
            #pragma unroll
            for (int r = 0; r < 4; ++r) {
                float v = cc[r];
                t3[i][2] = __builtin_amdgcn_fmed3f(v, t3[i][1], t3[i][2]);
                t3[i][1] = __builtin_amdgcn_fmed3f(v, t3[i][0], t3[i][1]);
                t3[i][0] = fmaxf(v, t3[i][0]);
            }
        }
    }
    // ---- h==3: one partially-valid tile (global rows 976..991); tiles 14,15
    //      are all-pad and skipped entirely ----
    if (h == 3) {
        const short8* p = lrow + (QT_PER - 3) * 128;
        short8 A0 = p[u0];
        short8 A1 = p[u1];
        #pragma unroll
        for (int i = 0; i < NT; ++i) {
            f32x4 cc = {0.f, 0.f, 0.f, 0.f};
            cc = __builtin_amdgcn_mfma_f32_16x16x32_bf16(A0, bq[i][0], cc, 0, 0, 0);
            cc = __builtin_amdgcn_mfma_f32_16x16x32_bf16(A1, bq[i][1], cc, 0, 0, 0);
            #pragma unroll
            for (int r = 0; r < 4; ++r) {
                int srow = 3 * QROWS_Q + (QT_PER - 3) * 16 + lg * 4 + r;
                float v = (srow < SSUP) ? cc[r] : -__builtin_inff();
                t3[i][2] = __builtin_amdgcn_fmed3f(v, t3[i][1], t3[i][2]);
                t3[i][1] = __builtin_amdgcn_fmed3f(v, t3[i][0], t3[i][1]);
                t3[i][0] = fmaxf(v, t3[i][0]);
            }
        }
    }

    // ---- merge top-3 across the 4 lane groups; store bf16 partial per row ----
    #pragma unroll
    for (int i = 0; i < NT; ++i) {
        float t0 = t3[i][0], t1 = t3[i][1], t2 = t3[i][2];
        #pragma unroll
        for (int m = 16; m <= 32; m <<= 1) {
            float o0 = __shfl_xor(t0, m, 64);
            float o1 = __shfl_xor(t1, m, 64);
            float o2 = __shfl_xor(t2, m, 64);
            t2 = __builtin_amdgcn_fmed3f(o0, t1, t2);
            t1 = __builtin_amdgcn_fmed3f(o0, t0, t1);
            t0 = fmaxf(o0, t0);
            t2 = __builtin_amdgcn_fmed3f(o1, t1, t2);
            t1 = __builtin_amdgcn_fmed3f(o1, t0, t1);
            t0 = fmaxf(o1, t0);
            t2 = __builtin_amdgcn_fmed3f(o2, t1, t2);
            t1 = __builtin_amdgcn_fmed3f(o2, t0, t1);
            t0 = fmaxf(o2, t0);
        }
        if (rows[i] < QROWS && (threadIdx.x & 63) < 16) {
            ushort* dst = partBase + (size_t)rows[i] * 3;
            dst[0] = f2bf(t0); dst[1] = f2bf(t1); dst[2] = f2bf(t2);
        }
    }
}

// Block = (pc, h): pc = (b*WAY+w)*QCHUNKS + chunk, h = support quarter.
// 1024 threads (16 waves), 32KB LDS, reg cap 64 -> 2 blocks/CU = 8 waves/SIMD.
__global__ __launch_bounds__(1024, 8)
void lpc_quarter(const float* __restrict__ qf, const ushort* __restrict__ Sb,
                 ushort* __restrict__ part) {
    const int gid = blockIdx.x;             // 0..999
    const int pc  = gid >> 2;
    const int h   = gid & 3;
    const int pair  = pc / QCHUNKS;         // b*WAY + w
    const int chunk = pc % QCHUNKS;
    const int b   = pair / WAY;
    const int qi0 = chunk * QI_PER_BLK;
    const int tid  = threadIdx.x;
    const int wid  = tid >> 6;              // 0..15
    const int lane = tid & 63;
    const int lr   = lane & 15;
    const int lg   = lane >> 4;

    __shared__ short8 ldsv[QROWS_Q * 8];    // 32768 B

    // ---- DMA this quarter's pre-swizzled panel into LDS (linear copy) ----
    const char* gsrc = (const char*)(Sb + ((size_t)pair * SPAD + (size_t)h * QROWS_Q) * D_);
    char* lbase = (char*)&ldsv[0];
    #pragma unroll
    for (int it = 0; it < 2; ++it) {
        int unit = it * 1024 + tid;         // 16B units, 2048 total
#if __has_builtin(__builtin_amdgcn_global_load_lds)
        __builtin_amdgcn_global_load_lds(
            (const __attribute__((address_space(1))) unsigned int*)(gsrc + (size_t)unit * 16),
            (__attribute__((address_space(3))) unsigned int*)(lbase + (size_t)unit * 16),
            16, 0, 0);
#else
        *(short8*)(lbase + (size_t)unit * 16) = *(const short8*)(gsrc + (size_t)unit * 16);
#endif
    }

    const float* Qc = qf + (size_t)(b * NWQ + qi0) * PQ * D_;
    ushort* partBase = part + (size_t)(pc * 4 + h) * QROWS * 3;

    const int u0 = lg ^ (lr & 7);
    const int u1 = (4 + lg) ^ (lr & 7);
    const short8* lrow = ldsv + (lr << 3);

    // 37 q-tiles over 16 waves: waves 0..4 own 3 tiles, waves 5..15 own 2.
    if (wid < QTILES_BLK - 2 * NWAVES)      // wid < 5
        wave_path<3>(lrow, u0, u1, lg, lr, wid, h, Qc, partBase);
    else
        wave_path<2>(lrow, u0, u1, lg, lr, wid, h, Qc, partBase);
}

// Merge the four quarters' per-row top-3 (bf16), sum per qi, write output.
__global__ __launch_bounds__(256)
void merge_kernel(const ushort* __restrict__ part, float* __restrict__ out) {
    const int pc  = blockIdx.x;             // 0..249
    const int tid = threadIdx.x;
    __shared__ float sums[QI_PER_BLK];
    if (tid < QI_PER_BLK) sums[tid] = 0.f;
    __syncthreads();

    for (int r = tid; r < QROWS; r += 256) {
        const ushort* p0 = part + ((size_t)(pc * 4 + 0) * QROWS + r) * 3;
        float t0 = bf2f(p0[0]), t1 = bf2f(p0[1]), t2 = bf2f(p0[2]);
        #pragma unroll
        for (int h = 1; h < 4; ++h) {
            const ushort* ph = part + ((size_t)(pc * 4 + h) * QROWS + r) * 3;
            #pragma unroll
            for (int j = 0; j < 3; ++j) {
                float v = bf2f(ph[j]);
                t2 = __builtin_amdgcn_fmed3f(v, t1, t2);
                t1 = __builtin_amdgcn_fmed3f(v, t0, t1);
                t0 = fmaxf(v, t0);
            }
        }
        atomicAdd(&sums[r / PQ], t0 + t1 + t2);
    }
    __syncthreads();
    if (tid < QI_PER_BLK) {
        int pair = pc / QCHUNKS, chunk = pc % QCHUNKS;
        int b = pair / WAY, w = pair % WAY;
        out[((size_t)b * NWQ + chunk * QI_PER_BLK + tid) * WAY + w] =
            sums[tid] * (1.0f / (PQ * 3.0f));
    }
}

// ---------------- fp32 fallback if ws too small ----------------
__global__ __launch_bounds__(256)
void lpc_kernel(const float* __restrict__ qfea,
                const float* __restrict__ sfea,
                float* __restrict__ out) {
    const int blk = blockIdx.x;
    const int w  = blk % WAY;
    const int qi = (blk / WAY) % NWQ;
    const int b  = blk / (WAY * NWQ);
    const int p  = threadIdx.x;
    float sum3 = 0.0f;
    if (p < PQ) {
        float qreg[D_];
        const float4* q4 = reinterpret_cast<const float4*>(
            qfea + (((size_t)b * NWQ + qi) * PQ + p) * D_);
        #pragma unroll
        for (int i = 0; i < D_ / 4; ++i) {
            float4 v = q4[i];
            qreg[4*i+0] = v.x; qreg[4*i+1] = v.y; qreg[4*i+2] = v.z; qreg[4*i+3] = v.w;
        }
        const float* sbase = sfea + ((size_t)b * WAY + w) * SSUP * D_;
        float t0 = -INFINITY, t1 = -INFINITY, t2 = -INFINITY;
        for (int s = 0; s < SSUP; ++s) {
            const float4* s4 = reinterpret_cast<const float4*>(sbase + (size_t)s * D_);
            float a0 = 0.f, a1 = 0.f, a2 = 0.f, a3 = 0.f;
            #pragma unroll
            for (int i = 0; i < D_ / 4; ++i) {
                float4 v = s4[i];
                a0 = fmaf(qreg[4*i+0], v.x, a0);
                a1 = fmaf(qreg[4*i+1], v.y, a1);
                a2 = fmaf(qreg[4*i+2], v.z, a2);
                a3 = fmaf(qreg[4*i+3], v.w, a3);
            }
            float dot = (a0 + a1) + (a2 + a3);
            float m0 = fminf(dot, t0);  t0 = fmaxf(dot, t0);
            float m1 = fminf(m0, t1);   t1 = fmaxf(m0, t1);
            t2 = fmaxf(m1, t2);
        }
        sum3 = t0 + t1 + t2;
    }
    __shared__ float red[256];
    red[threadIdx.x] = sum3;
    __syncthreads();
    #pragma unroll
    for (int off = 128; off > 0; off >>= 1) {
        if (threadIdx.x < off) red[threadIdx.x] += red[threadIdx.x + off];
        __syncthreads();
    }
    if (threadIdx.x == 0) out[blk] = red[0] * (1.0f / (PQ * 3.0f));
}

extern "C" void kernel_launch(void* const* d_in, const int* in_sizes, int n_in,
                              void* d_out, int out_size, void* d_ws, size_t ws_size,
                              hipStream_t stream) {
    const float* qf = (const float*)d_in[0];   // [2,75,196,64]
    const float* sf = (const float*)d_in[1];   // [2,5,5,196,64]
    float* out = (float*)d_out;                // [150,5]

    const size_t sBytes = (size_t)B_ * WAY * SPAD * D_ * sizeof(ushort);   // 1,310,720
    const size_t pBytes = (size_t)NPC * 4 * QROWS * 3 * sizeof(ushort);    // 3,528,000
    const size_t need   = sBytes + pBytes;                                 // ~4.84 MB

    if (ws_size >= need) {
        ushort* Sb   = (ushort*)d_ws;
        ushort* part = (ushort*)((char*)d_ws + sBytes);  // 16B-aligned
        const int NU = B_ * WAY * SPAD * 8;              // 81920 units
        cvt_s_kernel<<<(NU + 255) / 256, 256, 0, stream>>>(sf, Sb);
        lpc_quarter<<<NPC * 4, 1024, 0, stream>>>(qf, Sb, part);
        merge_kernel<<<NPC, 256, 0, stream>>>(part, out);
    } else {
        lpc_kernel<<<B_ * NWQ * WAY, 256, 0, stream>>>(qf, sf, out);
    }
}

// Round 8
// 45.898 us; speedup vs baseline: 1.2051x; 1.2051x over previous
//
#include <hip/hip_runtime.h>

#define B_    2
#define NWQ   75
#define PQ    196
#define D_    64
#define WAY   5
#define SSUP  980                  // support patches per (b, way)
#define SPAD  992                  // padded to 62*16
#define STILES 62
#define QI_PER_BLK 3
#define QCHUNKS 25                 // 75/3
#define QROWS 588                  // 3*196 query rows per chunk
#define QTILES_BLK 37              // ceil(588/16)
#define NPC  (B_ * WAY * QCHUNKS)  // 250 blocks
#define NWAVES 16                  // waves per block (1024 threads)

typedef __attribute__((ext_vector_type(8))) short short8;   // 8 bf16 = 4 VGPR
typedef __attribute__((ext_vector_type(4))) float f32x4;

__device__ __forceinline__ ushort f2bf(float f) {
    uint u = __builtin_bit_cast(uint, f);
    u = (u + 0x7FFFu + ((u >> 16) & 1u)) >> 16;
    return (ushort)u;
}

__device__ __forceinline__ short8 pack8(float4 a, float4 b) {
    short8 o;
    o[0] = (short)f2bf(a.x); o[1] = (short)f2bf(a.y);
    o[2] = (short)f2bf(a.z); o[3] = (short)f2bf(a.w);
    o[4] = (short)f2bf(b.x); o[5] = (short)f2bf(b.y);
    o[6] = (short)f2bf(b.z); o[7] = (short)f2bf(b.w);
    return o;
}

// fp32 -> bf16 support panel, padded to [2*5][992][64] (pad rows zero),
// PRE-SWIZZLED on 16B units (unit' = u ^ (row&7)) for linear LDS DMA.
__global__ __launch_bounds__(256)
void cvt_s_kernel(const float* __restrict__ in, ushort* __restrict__ out) {
    int i = blockIdx.x * blockDim.x + threadIdx.x;   // one 16B unit (8 bf16)
    const int NU = B_ * WAY * SPAD * 8;              // 79360
    if (i >= NU) return;
    int u  = i & 7;
    int r  = (i >> 3) % SPAD;
    int pr = i / (8 * SPAD);                         // b*WAY + w
    short8 o = {0,0,0,0,0,0,0,0};
    if (r < SSUP) {
        const float* src = in + ((size_t)(pr * SSUP + r) * D_ + u * 8);
        float4 f0 = *(const float4*)src;
        float4 f1 = *(const float4*)(src + 4);
        o = pack8(f0, f1);
    }
    int du = u ^ (r & 7);
    *(short8*)(out + ((size_t)(pr * SPAD + r) * 8 + du) * 8) = o;
}

// Per-wave path, NT q-tile streams. Each wave starts the s-tile loop at its
// own rotated offset (two wrap-free sub-loops) so the block's waves occupy
// DIFFERENT phases (ds_read / MFMA / insert) and the pipes overlap instead of
// being time-sliced by lockstep waves. Top-3 via exact max/med3 is
// order-independent, so rotation changes nothing numerically.
template<int NT>
__device__ __forceinline__ void wave_path(
    const short8* __restrict__ lrow, int u0, int u1, int lg, int lr, int wid,
    const float* __restrict__ Qc, float* __restrict__ sums) {

    short8 bq[NT][2];
    int rows[NT];
    #pragma unroll
    for (int i = 0; i < NT; ++i) {
        int row = (wid + NWAVES * i) * 16 + lr;
        rows[i] = row;
        int rc = (row < QROWS) ? row : 0;            // clamp; output guarded
        const float* qrow = Qc + (size_t)rc * D_;
        float4 fa = *(const float4*)(qrow + lg * 8);
        float4 fb = *(const float4*)(qrow + lg * 8 + 4);
        float4 fc = *(const float4*)(qrow + 32 + lg * 8);
        float4 fd = *(const float4*)(qrow + 32 + lg * 8 + 4);
        bq[i][0] = pack8(fa, fb);
        bq[i][1] = pack8(fc, fd);
    }

    float t3[NT][3];
    #pragma unroll
    for (int i = 0; i < NT; ++i) {
        t3[i][0] = -__builtin_inff(); t3[i][1] = -__builtin_inff(); t3[i][2] = -__builtin_inff();
    }

    // drain staging DMA + q loads, then block-wide barrier
    asm volatile("s_waitcnt vmcnt(0)" ::: "memory");
    __syncthreads();

    // Pad support rows are exact 0.0 sims; real top-3 >> 0 for this data, so
    // no tail masking needed anywhere.
    auto body = [&](int st) {
        const short8* p = lrow + st * 128;   // 16 rows x 8 units per tile
        short8 A0 = p[u0];
        short8 A1 = p[u1];
        __builtin_amdgcn_s_setprio(1);
        f32x4 c[NT];
        #pragma unroll
        for (int i = 0; i < NT; ++i) {
            f32x4 cc = {0.f, 0.f, 0.f, 0.f};
            cc = __builtin_amdgcn_mfma_f32_16x16x32_bf16(A0, bq[i][0], cc, 0, 0, 0);
            cc = __builtin_amdgcn_mfma_f32_16x16x32_bf16(A1, bq[i][1], cc, 0, 0, 0);
            c[i] = cc;
        }
        __builtin_amdgcn_s_setprio(0);
        #pragma unroll
        for (int i = 0; i < NT; ++i) {
            #pragma unroll
            for (int r = 0; r < 4; ++r) {
                float v = c[i][r];
                t3[i][2] = __builtin_amdgcn_fmed3f(v, t3[i][1], t3[i][2]);
                t3[i][1] = __builtin_amdgcn_fmed3f(v, t3[i][0], t3[i][1]);
                t3[i][0] = fmaxf(v, t3[i][0]);
            }
        }
    };

    const int off = (wid * STILES) / NWAVES;  // per-wave rotation: 0,3,7,...,58
    for (int st = off; st < STILES; ++st) body(st);
    for (int st = 0; st < off; ++st) body(st);

    // ---- merge top-3 across the 4 lane groups; accumulate per-qi sums ----
    #pragma unroll
    for (int i = 0; i < NT; ++i) {
        float t0 = t3[i][0], t1 = t3[i][1], t2 = t3[i][2];
        #pragma unroll
        for (int m = 16; m <= 32; m <<= 1) {
            float o0 = __shfl_xor(t0, m, 64);
            float o1 = __shfl_xor(t1, m, 64);
            float o2 = __shfl_xor(t2, m, 64);
            t2 = __builtin_amdgcn_fmed3f(o0, t1, t2);
            t1 = __builtin_amdgcn_fmed3f(o0, t0, t1);
            t0 = fmaxf(o0, t0);
            t2 = __builtin_amdgcn_fmed3f(o1, t1, t2);
            t1 = __builtin_amdgcn_fmed3f(o1, t0, t1);
            t0 = fmaxf(o1, t0);
            t2 = __builtin_amdgcn_fmed3f(o2, t1, t2);
            t1 = __builtin_amdgcn_fmed3f(o2, t0, t1);
            t0 = fmaxf(o2, t0);
        }
        const int lane = threadIdx.x & 63;
        float rs = (rows[i] < QROWS && lane < 16) ? (t0 + t1 + t2) : 0.f;
        int qi_l = (rows[i] >= PQ) + (rows[i] >= 2 * PQ);   // 0..2
        #pragma unroll
        for (int q = 0; q < QI_PER_BLK; ++q) {
            float vq = (qi_l == q) ? rs : 0.f;
            vq += __shfl_xor(vq, 1, 64);
            vq += __shfl_xor(vq, 2, 64);
            vq += __shfl_xor(vq, 4, 64);
            vq += __shfl_xor(vq, 8, 64);
            if (lane == 0 && vq != 0.f) atomicAdd(&sums[q], vq);
        }
    }
}

// Block = (pair, chunk of 3 qi). Full 992x64 bf16 pre-swizzled panel DMA'd to
// LDS once; 16 waves, rotated barrier-free tile loop; direct output.
__global__ __launch_bounds__(1024, 4)
void lpc_full(const float* __restrict__ qf, const ushort* __restrict__ Sb,
              float* __restrict__ out) {
    // bijective XCD swizzle: 25 blocks sharing a panel land on few XCDs
    const int gid = blockIdx.x;             // 0..249
    const int qq = NPC / 8, rr = NPC % 8;   // 31, 2
    const int xcd = gid % 8, idx = gid / 8;
    const int blk = (xcd < rr ? xcd * (qq + 1) : rr * (qq + 1) + (xcd - rr) * qq) + idx;

    const int pair  = blk / QCHUNKS;        // b*WAY + w
    const int chunk = blk % QCHUNKS;
    const int b   = pair / WAY, w = pair % WAY;
    const int qi0 = chunk * QI_PER_BLK;
    const int tid  = threadIdx.x;
    const int wid  = tid >> 6;              // 0..15
    const int lane = tid & 63;
    const int lr   = lane & 15;
    const int lg   = lane >> 4;

    __shared__ short8 ldsv[SPAD * 8];       // 126976 B (pre-swizzled layout)
    __shared__ float  sums[QI_PER_BLK];

    if (tid < QI_PER_BLK) sums[tid] = 0.f;

    // ---- DMA full pre-swizzled panel into LDS (linear copy) ----
    const char* gsrc = (const char*)(Sb + (size_t)pair * SPAD * D_);
    char* lbase = (char*)&ldsv[0];
    #pragma unroll
    for (int it = 0; it < 8; ++it) {
        int unit = it * 1024 + tid;         // 16B units, 7936 total
        if (unit < SPAD * 8) {
#if __has_builtin(__builtin_amdgcn_global_load_lds)
            __builtin_amdgcn_global_load_lds(
                (const __attribute__((address_space(1))) unsigned int*)(gsrc + (size_t)unit * 16),
                (__attribute__((address_space(3))) unsigned int*)(lbase + (size_t)unit * 16),
                16, 0, 0);
#else
            *(short8*)(lbase + (size_t)unit * 16) = *(const short8*)(gsrc + (size_t)unit * 16);
#endif
        }
    }

    const float* Qc = qf + (size_t)(b * NWQ + qi0) * PQ * D_;
    const int u0 = lg ^ (lr & 7);
    const int u1 = (4 + lg) ^ (lr & 7);
    const short8* lrow = ldsv + (lr << 3);

    // 37 q-tiles over 16 waves: waves 0..4 own 3 tiles, waves 5..15 own 2.
    if (wid < QTILES_BLK - 2 * NWAVES)      // wid < 5
        wave_path<3>(lrow, u0, u1, lg, lr, wid, Qc, sums);
    else
        wave_path<2>(lrow, u0, u1, lg, lr, wid, Qc, sums);

    __syncthreads();
    if (tid < QI_PER_BLK)
        out[((size_t)b * NWQ + qi0 + tid) * WAY + w] = sums[tid] * (1.0f / (PQ * 3.0f));
}

// ---------------- fp32 fallback if ws too small ----------------
__global__ __launch_bounds__(256)
void lpc_kernel(const float* __restrict__ qfea,
                const float* __restrict__ sfea,
                float* __restrict__ out) {
    const int blk = blockIdx.x;
    const int w  = blk % WAY;
    const int qi = (blk / WAY) % NWQ;
    const int b  = blk / (WAY * NWQ);
    const int p  = threadIdx.x;
    float sum3 = 0.0f;
    if (p < PQ) {
        float qreg[D_];
        const float4* q4 = reinterpret_cast<const float4*>(
            qfea + (((size_t)b * NWQ + qi) * PQ + p) * D_);
        #pragma unroll
        for (int i = 0; i < D_ / 4; ++i) {
            float4 v = q4[i];
            qreg[4*i+0] = v.x; qreg[4*i+1] = v.y; qreg[4*i+2] = v.z; qreg[4*i+3] = v.w;
        }
        const float* sbase = sfea + ((size_t)b * WAY + w) * SSUP * D_;
        float t0 = -INFINITY, t1 = -INFINITY, t2 = -INFINITY;
        for (int s = 0; s < SSUP; ++s) {
            const float4* s4 = reinterpret_cast<const float4*>(sbase + (size_t)s * D_);
            float a0 = 0.f, a1 = 0.f, a2 = 0.f, a3 = 0.f;
            #pragma unroll
            for (int i = 0; i < D_ / 4; ++i) {
                float4 v = s4[i];
                a0 = fmaf(qreg[4*i+0], v.x, a0);
                a1 = fmaf(qreg[4*i+1], v.y, a1);
                a2 = fmaf(qreg[4*i+2], v.z, a2);
                a3 = fmaf(qreg[4*i+3], v.w, a3);
            }
            float dot = (a0 + a1) + (a2 + a3);
            float m0 = fminf(dot, t0);  t0 = fmaxf(dot, t0);
            float m1 = fminf(m0, t1);   t1 = fmaxf(m0, t1);
            t2 = fmaxf(m1, t2);
        }
        sum3 = t0 + t1 + t2;
    }
    __shared__ float red[256];
    red[threadIdx.x] = sum3;
    __syncthreads();
    #pragma unroll
    for (int off = 128; off > 0; off >>= 1) {
        if (threadIdx.x < off) red[threadIdx.x] += red[threadIdx.x + off];
        __syncthreads();
    }
    if (threadIdx.x == 0) out[blk] = red[0] * (1.0f / (PQ * 3.0f));
}

extern "C" void kernel_launch(void* const* d_in, const int* in_sizes, int n_in,
                              void* d_out, int out_size, void* d_ws, size_t ws_size,
                              hipStream_t stream) {
    const float* qf = (const float*)d_in[0];   // [2,75,196,64]
    const float* sf = (const float*)d_in[1];   // [2,5,5,196,64]
    float* out = (float*)d_out;                // [150,5]

    const size_t sBytes = (size_t)B_ * WAY * SPAD * D_ * sizeof(ushort);  // 1,269,760

    if (ws_size >= sBytes) {
        ushort* Sb = (ushort*)d_ws;
        const int NU = B_ * WAY * SPAD * 8;    // 79360 units
        cvt_s_kernel<<<(NU + 255) / 256, 256, 0, stream>>>(sf, Sb);
        lpc_full<<<NPC, 1024, 0, stream>>>(qf, Sb, out);
    } else {
        lpc_kernel<<<B_ * NWQ * WAY, 256, 0, stream>>>(qf, sf, out);
    }
}

// Round 9
// 44.558 us; speedup vs baseline: 1.2413x; 1.0301x over previous
//
#include <hip/hip_runtime.h>

#define B_    2
#define NWQ   75
#define PQ    196
#define D_    64
#define WAY   5
#define SSUP  980                  // support patches per (b, way)
#define SPAD  992                  // padded to 62*16
#define STILES 62
#define QI_PER_BLK 3
#define QCHUNKS 25                 // 75/3
#define QROWS 588                  // 3*196 query rows per chunk
#define QTILES_BLK 37              // ceil(588/16)
#define NPC  (B_ * WAY * QCHUNKS)  // 250 blocks
#define NWAVES 16                  // waves per block (1024 threads)

typedef __attribute__((ext_vector_type(8))) short short8;   // 8 bf16 = 4 VGPR
typedef __attribute__((ext_vector_type(4))) float f32x4;
typedef __attribute__((address_space(3))) const short8 lds8_t;

__device__ __forceinline__ ushort f2bf(float f) {
    uint u = __builtin_bit_cast(uint, f);
    u = (u + 0x7FFFu + ((u >> 16) & 1u)) >> 16;
    return (ushort)u;
}

__device__ __forceinline__ short8 pack8(float4 a, float4 b) {
    short8 o;
    o[0] = (short)f2bf(a.x); o[1] = (short)f2bf(a.y);
    o[2] = (short)f2bf(a.z); o[3] = (short)f2bf(a.w);
    o[4] = (short)f2bf(b.x); o[5] = (short)f2bf(b.y);
    o[6] = (short)f2bf(b.z); o[7] = (short)f2bf(b.w);
    return o;
}

// raw ds_read_b128: issue WITHOUT an implicit wait; caller manages lgkmcnt.
__device__ __forceinline__ short8 ds_read128(lds8_t* p) {
    short8 d;
    asm volatile("ds_read_b128 %0, %1" : "=v"(d) : "v"(p));
    return d;
}
__device__ __forceinline__ void lgkm_fence() {
    asm volatile("s_waitcnt lgkmcnt(0)" ::: "memory");
    __builtin_amdgcn_sched_barrier(0);     // rule #18: stop hoisting past the wait
}

// fp32 -> bf16 support panel, padded to [2*5][992][64] (pad rows zero),
// PRE-SWIZZLED on 16B units (unit' = u ^ (row&7)) for linear LDS DMA.
__global__ __launch_bounds__(256)
void cvt_s_kernel(const float* __restrict__ in, ushort* __restrict__ out) {
    int i = blockIdx.x * blockDim.x + threadIdx.x;   // one 16B unit (8 bf16)
    const int NU = B_ * WAY * SPAD * 8;              // 79360
    if (i >= NU) return;
    int u  = i & 7;
    int r  = (i >> 3) % SPAD;
    int pr = i / (8 * SPAD);                         // b*WAY + w
    short8 o = {0,0,0,0,0,0,0,0};
    if (r < SSUP) {
        const float* src = in + ((size_t)(pr * SSUP + r) * D_ + u * 8);
        float4 f0 = *(const float4*)src;
        float4 f1 = *(const float4*)(src + 4);
        o = pack8(f0, f1);
    }
    int du = u ^ (r & 7);
    *(short8*)(out + ((size_t)(pr * SPAD + r) * 8 + du) * 8) = o;
}

// Hand-pipelined tile loop: inline-asm ds_read of tile st+1 issued BEFORE the
// MFMA+insert of tile st; lgkmcnt(0)+sched_barrier fence after the compute.
// 2-unrolled ping-pong (A/B fragment regs) so there are no register copies.
template<int NT>
__device__ __forceinline__ void wave_path(
    lds8_t* lrow, int u0, int u1, int wid,
    const float* __restrict__ Qc, float* __restrict__ sums) {

    short8 bq[NT][2];
    int rows[NT];
    #pragma unroll
    for (int i = 0; i < NT; ++i) {
        int lr = (int)(threadIdx.x & 15);
        int lg = (int)((threadIdx.x & 63) >> 4);
        int row = (wid + NWAVES * i) * 16 + lr;
        rows[i] = row;
        int rc = (row < QROWS) ? row : 0;            // clamp; output guarded
        const float* qrow = Qc + (size_t)rc * D_;
        float4 fa = *(const float4*)(qrow + lg * 8);
        float4 fb = *(const float4*)(qrow + lg * 8 + 4);
        float4 fc = *(const float4*)(qrow + 32 + lg * 8);
        float4 fd = *(const float4*)(qrow + 32 + lg * 8 + 4);
        bq[i][0] = pack8(fa, fb);
        bq[i][1] = pack8(fc, fd);
    }

    float t3[NT][3];
    #pragma unroll
    for (int i = 0; i < NT; ++i) {
        t3[i][0] = -__builtin_inff(); t3[i][1] = -__builtin_inff(); t3[i][2] = -__builtin_inff();
    }

    // drain staging DMA + q loads, then block-wide barrier
    asm volatile("s_waitcnt vmcnt(0)" ::: "memory");
    __syncthreads();

    // fused compute: 2*NT MFMA + 12*NT med3/max inserts on one fragment pair
    auto compute = [&](short8 A0, short8 A1) {
        #pragma unroll
        for (int i = 0; i < NT; ++i) {
            f32x4 cc = {0.f, 0.f, 0.f, 0.f};
            cc = __builtin_amdgcn_mfma_f32_16x16x32_bf16(A0, bq[i][0], cc, 0, 0, 0);
            cc = __builtin_amdgcn_mfma_f32_16x16x32_bf16(A1, bq[i][1], cc, 0, 0, 0);
            #pragma unroll
            for (int r = 0; r < 4; ++r) {
                float v = cc[r];
                t3[i][2] = __builtin_amdgcn_fmed3f(v, t3[i][1], t3[i][2]);
                t3[i][1] = __builtin_amdgcn_fmed3f(v, t3[i][0], t3[i][1]);
                t3[i][0] = fmaxf(v, t3[i][0]);
            }
        }
    };

    lds8_t* p0 = lrow + u0;                  // tile stride = 128 short8 units
    lds8_t* p1 = lrow + u1;

    // prologue: load tile 0 into A
    short8 A0 = ds_read128(p0);
    short8 A1 = ds_read128(p1);
    lgkm_fence();

    // main: tiles 0..59 in ping-pong pairs (B prefetched during A compute)
    for (int st = 0; st < STILES - 2; st += 2) {
        p0 += 128; p1 += 128;
        short8 B0 = ds_read128(p0);          // issue tile st+1
        short8 B1 = ds_read128(p1);
        compute(A0, A1);                     // tile st
        lgkm_fence();
        p0 += 128; p1 += 128;
        A0 = ds_read128(p0);                 // issue tile st+2
        A1 = ds_read128(p1);
        compute(B0, B1);                     // tile st+1
        lgkm_fence();
    }
    // epilogue: tiles 60, 61
    {
        p0 += 128; p1 += 128;
        short8 B0 = ds_read128(p0);
        short8 B1 = ds_read128(p1);
        compute(A0, A1);                     // tile 60
        lgkm_fence();
        compute(B0, B1);                     // tile 61 (pad rows sim=0, never top-3)
    }

    // ---- merge top-3 across the 4 lane groups; accumulate per-qi sums ----
    #pragma unroll
    for (int i = 0; i < NT; ++i) {
        float t0 = t3[i][0], t1 = t3[i][1], t2 = t3[i][2];
        #pragma unroll
        for (int m = 16; m <= 32; m <<= 1) {
            float o0 = __shfl_xor(t0, m, 64);
            float o1 = __shfl_xor(t1, m, 64);
            float o2 = __shfl_xor(t2, m, 64);
            t2 = __builtin_amdgcn_fmed3f(o0, t1, t2);
            t1 = __builtin_amdgcn_fmed3f(o0, t0, t1);
            t0 = fmaxf(o0, t0);
            t2 = __builtin_amdgcn_fmed3f(o1, t1, t2);
            t1 = __builtin_amdgcn_fmed3f(o1, t0, t1);
            t0 = fmaxf(o1, t0);
            t2 = __builtin_amdgcn_fmed3f(o2, t1, t2);
            t1 = __builtin_amdgcn_fmed3f(o2, t0, t1);
            t0 = fmaxf(o2, t0);
        }
        const int lane = threadIdx.x & 63;
        float rs = (rows[i] < QROWS && lane < 16) ? (t0 + t1 + t2) : 0.f;
        int qi_l = (rows[i] >= PQ) + (rows[i] >= 2 * PQ);   // 0..2
        #pragma unroll
        for (int q = 0; q < QI_PER_BLK; ++q) {
            float vq = (qi_l == q) ? rs : 0.f;
            vq += __shfl_xor(vq, 1, 64);
            vq += __shfl_xor(vq, 2, 64);
            vq += __shfl_xor(vq, 4, 64);
            vq += __shfl_xor(vq, 8, 64);
            if (lane == 0 && vq != 0.f) atomicAdd(&sums[q], vq);
        }
    }
}

// Block = (pair, chunk of 3 qi). Full 992x64 bf16 pre-swizzled panel DMA'd to
// LDS once; 16 waves, hand-pipelined barrier-free tile loop; direct output.
__global__ __launch_bounds__(1024)
void lpc_full(const float* __restrict__ qf, const ushort* __restrict__ Sb,
              float* __restrict__ out) {
    // bijective XCD swizzle: 25 blocks sharing a panel land on few XCDs
    const int gid = blockIdx.x;             // 0..249
    const int qq = NPC / 8, rr = NPC % 8;   // 31, 2
    const int xcd = gid % 8, idx = gid / 8;
    const int blk = (xcd < rr ? xcd * (qq + 1) : rr * (qq + 1) + (xcd - rr) * qq) + idx;

    const int pair  = blk / QCHUNKS;        // b*WAY + w
    const int chunk = blk % QCHUNKS;
    const int b   = pair / WAY, w = pair % WAY;
    const int qi0 = chunk * QI_PER_BLK;
    const int tid  = threadIdx.x;
    const int wid  = tid >> 6;              // 0..15
    const int lane = tid & 63;
    const int lr   = lane & 15;
    const int lg   = lane >> 4;

    __shared__ short8 ldsv[SPAD * 8];       // 126976 B (pre-swizzled layout)
    __shared__ float  sums[QI_PER_BLK];

    if (tid < QI_PER_BLK) sums[tid] = 0.f;

    // ---- DMA full pre-swizzled panel into LDS (linear copy) ----
    const char* gsrc = (const char*)(Sb + (size_t)pair * SPAD * D_);
    char* lbase = (char*)&ldsv[0];
    #pragma unroll
    for (int it = 0; it < 8; ++it) {
        int unit = it * 1024 + tid;         // 16B units, 7936 total
        if (unit < SPAD * 8) {
#if __has_builtin(__builtin_amdgcn_global_load_lds)
            __builtin_amdgcn_global_load_lds(
                (const __attribute__((address_space(1))) unsigned int*)(gsrc + (size_t)unit * 16),
                (__attribute__((address_space(3))) unsigned int*)(lbase + (size_t)unit * 16),
                16, 0, 0);
#else
            *(short8*)(lbase + (size_t)unit * 16) = *(const short8*)(gsrc + (size_t)unit * 16);
#endif
        }
    }

    const float* Qc = qf + (size_t)(b * NWQ + qi0) * PQ * D_;
    const int u0 = lg ^ (lr & 7);
    const int u1 = (4 + lg) ^ (lr & 7);
    lds8_t* lrow = (lds8_t*)(ldsv + (lr << 3));

    // 37 q-tiles over 16 waves: waves 0..4 own 3 tiles, waves 5..15 own 2.
    if (wid < QTILES_BLK - 2 * NWAVES)      // wid < 5
        wave_path<3>(lrow, u0, u1, wid, Qc, sums);
    else
        wave_path<2>(lrow, u0, u1, wid, Qc, sums);

    __syncthreads();
    if (tid < QI_PER_BLK)
        out[((size_t)b * NWQ + qi0 + tid) * WAY + w] = sums[tid] * (1.0f / (PQ * 3.0f));
}

// ---------------- fp32 fallback if ws too small ----------------
__global__ __launch_bounds__(256)
void lpc_kernel(const float* __restrict__ qfea,
                const float* __restrict__ sfea,
                float* __restrict__ out) {
    const int blk = blockIdx.x;
    const int w  = blk % WAY;
    const int qi = (blk / WAY) % NWQ;
    const int b  = blk / (WAY * NWQ);
    const int p  = threadIdx.x;
    float sum3 = 0.0f;
    if (p < PQ) {
        float qreg[D_];
        const float4* q4 = reinterpret_cast<const float4*>(
            qfea + (((size_t)b * NWQ + qi) * PQ + p) * D_);
        #pragma unroll
        for (int i = 0; i < D_ / 4; ++i) {
            float4 v = q4[i];
            qreg[4*i+0] = v.x; qreg[4*i+1] = v.y; qreg[4*i+2] = v.z; qreg[4*i+3] = v.w;
        }
        const float* sbase = sfea + ((size_t)b * WAY + w) * SSUP * D_;
        float t0 = -INFINITY, t1 = -INFINITY, t2 = -INFINITY;
        for (int s = 0; s < SSUP; ++s) {
            const float4* s4 = reinterpret_cast<const float4*>(sbase + (size_t)s * D_);
            float a0 = 0.f, a1 = 0.f, a2 = 0.f, a3 = 0.f;
            #pragma unroll
            for (int i = 0; i < D_ / 4; ++i) {
                float4 v = s4[i];
                a0 = fmaf(qreg[4*i+0], v.x, a0);
                a1 = fmaf(qreg[4*i+1], v.y, a1);
                a2 = fmaf(qreg[4*i+2], v.z, a2);
                a3 = fmaf(qreg[4*i+3], v.w, a3);
            }
            float dot = (a0 + a1) + (a2 + a3);
            float m0 = fminf(dot, t0);  t0 = fmaxf(dot, t0);
            float m1 = fminf(m0, t1);   t1 = fmaxf(m0, t1);
            t2 = fmaxf(m1, t2);
        }
        sum3 = t0 + t1 + t2;
    }
    __shared__ float red[256];
    red[threadIdx.x] = sum3;
    __syncthreads();
    #pragma unroll
    for (int off = 128; off > 0; off >>= 1) {
        if (threadIdx.x < off) red[threadIdx.x] += red[threadIdx.x + off];
        __syncthreads();
    }
    if (threadIdx.x == 0) out[blk] = red[0] * (1.0f / (PQ * 3.0f));
}

extern "C" void kernel_launch(void* const* d_in, const int* in_sizes, int n_in,
                              void* d_out, int out_size, void* d_ws, size_t ws_size,
                              hipStream_t stream) {
    const float* qf = (const float*)d_in[0];   // [2,75,196,64]
    const float* sf = (const float*)d_in[1];   // [2,5,5,196,64]
    float* out = (float*)d_out;                // [150,5]

    const size_t sBytes = (size_t)B_ * WAY * SPAD * D_ * sizeof(ushort);  // 1,269,760

    if (ws_size >= sBytes) {
        ushort* Sb = (ushort*)d_ws;
        const int NU = B_ * WAY * SPAD * 8;    // 79360 units
        cvt_s_kernel<<<(NU + 255) / 256, 256, 0, stream>>>(sf, Sb);
        lpc_full<<<NPC, 1024, 0, stream>>>(qf, Sb, out);
    } else {
        lpc_kernel<<<B_ * NWQ * WAY, 256, 0, stream>>>(qf, sf, out);
    }
}